// Round 3
// baseline (526.615 us; speedup 1.0000x reference)
//
#include <hip/hip_runtime.h>
#include <stdint.h>

// out[m,n] = sum_k x[m,k]*W[n,k] + sum_r y[m,r]*A[n,r],  y = x @ B^T
// M=256, N=8192, K=8192, R=16. fp32 in/out; bf16 MFMA compute (thr 0.18).
//
// R3 design: BARRIER-FREE K-loop. No LDS. Each wave owns a 128m x 32n x 2048k
// job: a-frags streamed from pre-swizzled bf16 x (L2-resident, coalesced 1KB
// dwordx4), W fp32 prefetched 1 iter ahead in registers -> RNE pack -> MFMA.
// Without barriers the compiler emits fine-grained vmcnt(N): prefetch stays
// in flight across iterations (the AITER pattern a barriered loop can't do).

#define DM 256
#define DK 8192
#define DN 8192
#define RLORA 16
#define KSPLIT 4
#define KCHUNK (DK / KSPLIT)    // 2048
#define BK 64
#define NITER (KCHUNK / BK)     // 32

typedef short bf16x8 __attribute__((ext_vector_type(8)));   // 4 VGPRs
typedef float f32x4v __attribute__((ext_vector_type(4)));

__device__ __forceinline__ unsigned short f2bf(float f) {
  unsigned u = __builtin_bit_cast(unsigned, f);
  u += 0x7FFFu + ((u >> 16) & 1u);           // RNE
  return (unsigned short)(u >> 16);
}

__device__ __forceinline__ bf16x8 pack8(float4 a, float4 b) {
  bf16x8 r;
  r[0] = (short)f2bf(a.x); r[1] = (short)f2bf(a.y);
  r[2] = (short)f2bf(a.z); r[3] = (short)f2bf(a.w);
  r[4] = (short)f2bf(b.x); r[5] = (short)f2bf(b.y);
  r[6] = (short)f2bf(b.z); r[7] = (short)f2bf(b.w);
  return r;
}

// ---------------------------------------------------------------------------
// prep_x: x -> bf16 in MFMA-frag-linear layout, + partial y = x @ B^T (fp32
// atomics into y32). grid (8 k-slices, 64 m-groups of 4 rows), 256 thr.
// Frag id f = ((mh*128 + I)*2 + s)*8 + mt ; within frag lane (oct*16+r) holds
// x[mh*128+mt*16+r][I*64+s*32+oct*8 .. +8)  (A-operand layout, m89-verified).
__global__ __launch_bounds__(256) void prep_x(
    const float* __restrict__ x, const float* __restrict__ Bm,
    unsigned short* __restrict__ xb, float* __restrict__ y32) {
  const int ks = blockIdx.x;            // k-slice of 1024
  const int m0 = blockIdx.y * 4;
  const int t = threadIdx.x;
  const int k = ks * 1024 + t * 4;      // one float4 per row
  const int I = k >> 6, s = (k >> 5) & 1, oct = (k >> 3) & 3;
  const int ebyte = (k & 4) * 2;        // 0 or 8 within the 16B lane slot
  float4 xv[4];
#pragma unroll
  for (int i = 0; i < 4; ++i) {
    const int m = m0 + i;
    const int mh = m >> 7, mt = (m >> 4) & 7, r = m & 15;
    xv[i] = *(const float4*)(x + (size_t)m * DK + k);
    ushort4 h;
    h.x = f2bf(xv[i].x); h.y = f2bf(xv[i].y);
    h.z = f2bf(xv[i].z); h.w = f2bf(xv[i].w);
    const int frag = ((mh * 128 + I) * 2 + s) * 8 + mt;
    *(ushort4*)((char*)xb + (size_t)frag * 1024 + (oct * 16 + r) * 16 + ebyte) = h;
  }
  float acc[4][RLORA];
#pragma unroll
  for (int r = 0; r < RLORA; ++r) {
    float4 b = *(const float4*)(Bm + (size_t)r * DK + k);
#pragma unroll
    for (int i = 0; i < 4; ++i)
      acc[i][r] = xv[i].x * b.x + xv[i].y * b.y + xv[i].z * b.z + xv[i].w * b.w;
  }
#pragma unroll
  for (int off = 32; off >= 1; off >>= 1)
#pragma unroll
    for (int i = 0; i < 4; ++i)
#pragma unroll
      for (int r = 0; r < RLORA; ++r)
        acc[i][r] += __shfl_xor(acc[i][r], off, 64);
  __shared__ float red[4][4][RLORA];
  const int lane = t & 63, wv = t >> 6;
  if (lane == 0) {
#pragma unroll
    for (int i = 0; i < 4; ++i)
#pragma unroll
      for (int r = 0; r < RLORA; ++r) red[wv][i][r] = acc[i][r];
  }
  __syncthreads();
  if (t < 64) {
    int i = t >> 4, r = t & 15;
    float sum = red[0][i][r] + red[1][i][r] + red[2][i][r] + red[3][i][r];
    atomicAdd(y32 + (m0 + i) * RLORA + r, sum);
  }
}

// y32 fp32 [256][16] -> yb bf16 frags: frag fy = mh*8+mt, lane (oct*16+r) =
// y[mh*128+mt*16+r][oct*8+e] zero-padded past col 16.  16 KB total.
__global__ __launch_bounds__(256) void pack_y(
    const float* __restrict__ y32, unsigned short* __restrict__ yb) {
  int slot = blockIdx.x * 256 + threadIdx.x;   // 0..2047, 8B each
  int fy = slot >> 7, q = slot & 127;
  int lane = q >> 1, e0 = (q & 1) * 4;
  int oct = lane >> 4, r = lane & 15;
  int mh = fy >> 3, mt = fy & 7;
  int m = mh * 128 + mt * 16 + r;
  ushort4 h;
  int c = oct * 8 + e0;
  h.x = (c + 0 < RLORA) ? f2bf(y32[m * RLORA + c + 0]) : (unsigned short)0;
  h.y = (c + 1 < RLORA) ? f2bf(y32[m * RLORA + c + 1]) : (unsigned short)0;
  h.z = (c + 2 < RLORA) ? f2bf(y32[m * RLORA + c + 2]) : (unsigned short)0;
  h.w = (c + 3 < RLORA) ? f2bf(y32[m * RLORA + c + 3]) : (unsigned short)0;
  *(ushort4*)((char*)yb + (size_t)slot * 8) = h;
}

// ---------------------------------------------------------------------------
// Main GEMM. 512 blocks x 256 thr; wave gid -> (nt 0..255, kz 0..3, mh 0..1).
// No __shared__, no __syncthreads in this kernel.
__global__ __launch_bounds__(256, 2) void lora_gemm(
    const unsigned short* __restrict__ xb,   // frag-linear bf16 x
    const float* __restrict__ W,             // [8192][8192] fp32
    const unsigned short* __restrict__ yb,   // y frags (16 KB)
    const float* __restrict__ Aw,            // [8192][16] fp32
    float* __restrict__ out,                 // [256][8192] fp32
    float* __restrict__ part) {              // [KSPLIT][256][8192] or null
  const int tid = threadIdx.x;
  const int lane = tid & 63;
  const int wave = tid >> 6;
  const int gid = blockIdx.x * 4 + wave;
  const int nt = gid & 255;                  // consecutive waves -> adjacent n
  const int tmp = gid >> 8;
  const int kz = tmp & 3;
  const int mh = tmp >> 2;
  const int n0 = nt * 32;
  const int kb = kz * KCHUNK;
  const int qr = lane & 15, quad = lane >> 4;

  const float* w0 = W + (size_t)(n0 + qr) * DK + kb + quad * 8;
  const float* w1 = w0 + (size_t)16 * DK;
  // a-frag stream: 16 frags (s*8+mt) of 1KB per iteration, fully coalesced
  const bf16x8* ap = (const bf16x8*)xb +
                     (size_t)(mh * 128 + kz * NITER) * 16 * 64 + lane;

  f32x4v acc[8][2];
#pragma unroll
  for (int mt = 0; mt < 8; ++mt)
#pragma unroll
    for (int j = 0; j < 2; ++j) acc[mt][j] = (f32x4v){0.f, 0.f, 0.f, 0.f};

  // prologue: W(0) -> F
  float4 F[2][2][2];                         // [j][s][half]
#pragma unroll
  for (int s = 0; s < 2; ++s)
#pragma unroll
    for (int h = 0; h < 2; ++h) {
      F[0][s][h] = *(const float4*)(w0 + s * 32 + h * 4);
      F[1][s][h] = *(const float4*)(w1 + s * 32 + h * 4);
    }

  for (int it = 0; it < NITER - 1; ++it) {
    // a-frags for THIS iter (L2 hits, issued early; waits are fine-grained)
    bf16x8 av[16];
#pragma unroll
    for (int u = 0; u < 16; ++u) av[u] = ap[u * 64];
    ap += 16 * 64;
    // pack current W (frees F), then prefetch next W (stays in flight
    // through this iteration's MFMAs -- no barrier to drain it)
    bf16x8 b[2][2];
#pragma unroll
    for (int j = 0; j < 2; ++j)
#pragma unroll
      for (int s = 0; s < 2; ++s) b[j][s] = pack8(F[j][s][0], F[j][s][1]);
    float4 g[2][2][2];
#pragma unroll
    for (int s = 0; s < 2; ++s)
#pragma unroll
      for (int h = 0; h < 2; ++h) {
        g[0][s][h] = *(const float4*)(w0 + BK + s * 32 + h * 4);
        g[1][s][h] = *(const float4*)(w1 + BK + s * 32 + h * 4);
      }
    w0 += BK; w1 += BK;
#pragma unroll
    for (int s = 0; s < 2; ++s)
#pragma unroll
      for (int mt = 0; mt < 8; ++mt) {
        acc[mt][0] = __builtin_amdgcn_mfma_f32_16x16x32_bf16(
            av[s * 8 + mt], b[0][s], acc[mt][0], 0, 0, 0);
        acc[mt][1] = __builtin_amdgcn_mfma_f32_16x16x32_bf16(
            av[s * 8 + mt], b[1][s], acc[mt][1], 0, 0, 0);
      }
#pragma unroll
    for (int j = 0; j < 2; ++j)
#pragma unroll
      for (int s = 0; s < 2; ++s)
#pragma unroll
        for (int h = 0; h < 2; ++h) F[j][s][h] = g[j][s][h];
  }
  {  // final iteration (no W prefetch -- avoids OOB read past W)
    bf16x8 av[16];
#pragma unroll
    for (int u = 0; u < 16; ++u) av[u] = ap[u * 64];
    bf16x8 b[2][2];
#pragma unroll
    for (int j = 0; j < 2; ++j)
#pragma unroll
      for (int s = 0; s < 2; ++s) b[j][s] = pack8(F[j][s][0], F[j][s][1]);
#pragma unroll
    for (int s = 0; s < 2; ++s)
#pragma unroll
      for (int mt = 0; mt < 8; ++mt) {
        acc[mt][0] = __builtin_amdgcn_mfma_f32_16x16x32_bf16(
            av[s * 8 + mt], b[0][s], acc[mt][0], 0, 0, 0);
        acc[mt][1] = __builtin_amdgcn_mfma_f32_16x16x32_bf16(
            av[s * 8 + mt], b[1][s], acc[mt][1], 0, 0, 0);
      }
  }

  if (kz == 0) {  // LoRA step: one extra K=32 MFMA round (cols >=16 are zero)
    float4 z = {0.f, 0.f, 0.f, 0.f};
    const float* a0 = Aw + (size_t)(n0 + qr) * RLORA + quad * 8;
    const float* a1 = a0 + (size_t)16 * RLORA;
    float4 p00 = (quad < 2) ? *(const float4*)(a0) : z;
    float4 p01 = (quad < 2) ? *(const float4*)(a0 + 4) : z;
    float4 p10 = (quad < 2) ? *(const float4*)(a1) : z;
    float4 p11 = (quad < 2) ? *(const float4*)(a1 + 4) : z;
    bf16x8 b0 = pack8(p00, p01), b1 = pack8(p10, p11);
    const bf16x8* yp = (const bf16x8*)yb + mh * 8 * 64 + lane;
#pragma unroll
    for (int mt = 0; mt < 8; ++mt) {
      bf16x8 av = yp[mt * 64];
      acc[mt][0] = __builtin_amdgcn_mfma_f32_16x16x32_bf16(av, b0, acc[mt][0], 0, 0, 0);
      acc[mt][1] = __builtin_amdgcn_mfma_f32_16x16x32_bf16(av, b1, acc[mt][1], 0, 0, 0);
    }
  }

  // epilogue: C/D col=lane&15 (n), row=quad*4+rg (m)  [m89-verified]
  const size_t obase = (size_t)(mh * 128 + quad * 4) * DN + n0 + qr;
  if (part) {
    float* pb = part + (size_t)kz * DM * DN + obase;
#pragma unroll
    for (int mt = 0; mt < 8; ++mt)
#pragma unroll
      for (int rg = 0; rg < 4; ++rg) {
        float* row = pb + (size_t)(mt * 16 + rg) * DN;
        row[0] = acc[mt][0][rg];
        row[16] = acc[mt][1][rg];
      }
  } else {
    float* ob = out + obase;
#pragma unroll
    for (int mt = 0; mt < 8; ++mt)
#pragma unroll
      for (int rg = 0; rg < 4; ++rg) {
        float* row = ob + (size_t)(mt * 16 + rg) * DN;
        atomicAdd(row, acc[mt][0][rg]);
        atomicAdd(row + 16, acc[mt][1][rg]);
      }
  }
}

// out = sum_kz part[kz]  (fully overwrites out).  grid 2048 x 256.
__global__ __launch_bounds__(256) void reduce_k(
    const float* __restrict__ part, float* __restrict__ out) {
  size_t i = ((size_t)blockIdx.x * 256 + threadIdx.x) * 4;
  float4 s = *(const float4*)(part + i);
#pragma unroll
  for (int kz = 1; kz < KSPLIT; ++kz) {
    float4 v = *(const float4*)(part + (size_t)kz * DM * DN + i);
    s.x += v.x; s.y += v.y; s.z += v.z; s.w += v.w;
  }
  *(float4*)(out + i) = s;
}

// ---------------------------------------------------------------------------
extern "C" void kernel_launch(void* const* d_in, const int* in_sizes, int n_in,
                              void* d_out, int out_size, void* d_ws, size_t ws_size,
                              hipStream_t stream) {
  const float* x  = (const float*)d_in[0];   // [4,64,8192]
  const float* W  = (const float*)d_in[1];   // [8192,8192]
  const float* A  = (const float*)d_in[2];   // [8192,16]
  const float* Bm = (const float*)d_in[3];   // [16,8192]
  float* out = (float*)d_out;

  unsigned short* xb = (unsigned short*)d_ws;             // 4 MiB swizzled
  unsigned short* yb = (unsigned short*)((char*)d_ws + (4u << 20));  // 16 KiB
  float* y32 = (float*)((char*)yb + 16384);               // 16 KiB
  size_t base_bytes = (4u << 20) + 16384 + 16384;
  size_t part_bytes = (size_t)KSPLIT * DM * DN * 4;       // 32 MiB
  bool use_part = ws_size >= base_bytes + part_bytes;
  float* part = use_part ? (float*)((char*)d_ws + base_bytes) : nullptr;

  if (!use_part)
    hipMemsetAsync(d_out, 0, (size_t)out_size * sizeof(float), stream);
  hipMemsetAsync(y32, 0, (size_t)DM * RLORA * sizeof(float), stream);
  prep_x<<<dim3(8, 64), 256, 0, stream>>>(x, Bm, xb, y32);
  pack_y<<<8, 256, 0, stream>>>(y32, yb);
  lora_gemm<<<512, 256, 0, stream>>>(xb, W, yb, A, out, part);
  if (use_part) reduce_k<<<2048, 256, 0, stream>>>(part, out);
}

// Round 4
// 452.610 us; speedup vs baseline: 1.1635x; 1.1635x over previous
//
#include <hip/hip_runtime.h>
#include <stdint.h>

// out[m,n] = sum_k x[m,k]*W[n,k] + sum_r y[m,r]*A[n,r],  y = x @ B^T
// M=256, N=8192, K=8192, R=16. fp32 in/out; bf16 MFMA compute (thr 0.18).
//
// R4: one 1024-thr block per CU, tile 256m x 256n (W read once), KSPLIT=8.
// x: bf16 pre-swizzled frag-linear, staged via global_load_lds (double buf).
// W: 64 B/thread fp32 -> RNE pack -> ds_write_b128 bf16 double buf.
// One barrier/iter; delivery (96 KB/iter/CU) is the pacing term, MFMA+LDS
// co-schedule under it.

#define DM 256
#define DK 8192
#define DN 8192
#define RLORA 16

#define TN 256
#define BK 64
#define KSPLIT 8
#define KCHUNK (DK / KSPLIT)    // 1024
#define NITER (KCHUNK / BK)     // 16

typedef short bf16x8 __attribute__((ext_vector_type(8)));   // 4 VGPRs
typedef float f32x4v __attribute__((ext_vector_type(4)));

typedef __attribute__((address_space(1))) const unsigned char glbc_u8;
typedef __attribute__((address_space(3))) unsigned char lds_u8;

__device__ __forceinline__ unsigned short f2bf(float f) {
  unsigned u = __builtin_bit_cast(unsigned, f);
  u += 0x7FFFu + ((u >> 16) & 1u);           // RNE
  return (unsigned short)(u >> 16);
}

__device__ __forceinline__ bf16x8 pack8(float4 a, float4 b) {
  bf16x8 r;
  r[0] = (short)f2bf(a.x); r[1] = (short)f2bf(a.y);
  r[2] = (short)f2bf(a.z); r[3] = (short)f2bf(a.w);
  r[4] = (short)f2bf(b.x); r[5] = (short)f2bf(b.y);
  r[6] = (short)f2bf(b.z); r[7] = (short)f2bf(b.w);
  return r;
}

// ---------------------------------------------------------------------------
// prep_x: x -> bf16 in the gemm's frag-linear chunk order, + partial
// y = x @ B^T into y32. grid (8 k-slices, 64 m-groups of 4 rows), 256 thr.
// Chunk order: chunk = ((kz*16+it)*32 + s*16 + g)*64 + oct*16 + r, 16 B each,
// holding x[g*16+r][kz*1024 + it*64 + s*32 + oct*8 .. +8).
__global__ __launch_bounds__(256) void prep_x(
    const float* __restrict__ x, const float* __restrict__ Bm,
    unsigned short* __restrict__ xb, float* __restrict__ y32) {
  const int ks = blockIdx.x;
  const int m0 = blockIdx.y * 4;
  const int t = threadIdx.x;
  const int k = ks * 1024 + t * 4;
  const int it = (k >> 6) & 15, s = (k >> 5) & 1, oct = (k >> 3) & 3;
  const int e = k & 7;                       // 0 or 4
  float4 xv[4];
#pragma unroll
  for (int i = 0; i < 4; ++i) {
    const int m = m0 + i;
    const int g = m >> 4, r = m & 15;
    xv[i] = *(const float4*)(x + (size_t)m * DK + k);
    ushort4 h;
    h.x = f2bf(xv[i].x); h.y = f2bf(xv[i].y);
    h.z = f2bf(xv[i].z); h.w = f2bf(xv[i].w);
    const size_t chunk = (size_t)((ks * 16 + it) * 32 + s * 16 + g) * 64 + oct * 16 + r;
    *(ushort4*)(xb + chunk * 8 + e) = h;
  }
  float acc[4][RLORA];
#pragma unroll
  for (int r = 0; r < RLORA; ++r) {
    float4 b = *(const float4*)(Bm + (size_t)r * DK + k);
#pragma unroll
    for (int i = 0; i < 4; ++i)
      acc[i][r] = xv[i].x * b.x + xv[i].y * b.y + xv[i].z * b.z + xv[i].w * b.w;
  }
#pragma unroll
  for (int off = 32; off >= 1; off >>= 1)
#pragma unroll
    for (int i = 0; i < 4; ++i)
#pragma unroll
      for (int r = 0; r < RLORA; ++r)
        acc[i][r] += __shfl_xor(acc[i][r], off, 64);
  __shared__ float red[4][4][RLORA];
  const int lane = t & 63, wv = t >> 6;
  if (lane == 0) {
#pragma unroll
    for (int i = 0; i < 4; ++i)
#pragma unroll
      for (int r = 0; r < RLORA; ++r) red[wv][i][r] = acc[i][r];
  }
  __syncthreads();
  if (t < 64) {
    int i = t >> 4, r = t & 15;
    float sum = red[0][i][r] + red[1][i][r] + red[2][i][r] + red[3][i][r];
    atomicAdd(y32 + (m0 + i) * RLORA + r, sum);
  }
}

// y32 fp32 [256][16] -> yb A-operand frags: frag fy = m/16 (1 KB), lane slot
// (oct*16+r) holds y[fy*16+r][oct*8+e], zero past col 16.  16 KB. grid 4x256.
__global__ __launch_bounds__(256) void pack_y(
    const float* __restrict__ y32, unsigned short* __restrict__ yb) {
  int slot = blockIdx.x * 256 + threadIdx.x;   // 0..1023 16B slots
  int fy = slot >> 6, l = slot & 63;
  int oct = l >> 4, r = l & 15;
  int m = fy * 16 + r;
  unsigned short v[8];
#pragma unroll
  for (int e = 0; e < 8; ++e) {
    int c = oct * 8 + e;
    v[e] = (c < RLORA) ? f2bf(y32[m * RLORA + c]) : (unsigned short)0;
  }
  *(ushort4*)(yb + slot * 8) = make_ushort4(v[0], v[1], v[2], v[3]);
  *(ushort4*)(yb + slot * 8 + 4) = make_ushort4(v[4], v[5], v[6], v[7]);
}

// ---------------------------------------------------------------------------
// Main GEMM. grid (32, 8), 1024 thr = 16 waves as 4m x 4n (wave 64m x 64n).
__global__ __launch_bounds__(1024) void lora_gemm(
    const unsigned short* __restrict__ xb,   // frag-linear bf16 x
    const float* __restrict__ W,             // [8192][8192] fp32
    const unsigned short* __restrict__ yb,   // y frags (16 KB)
    const float* __restrict__ Aw,            // [8192][16] fp32
    float* __restrict__ out,                 // [256][8192] fp32
    float* __restrict__ part) {              // [KSPLIT][256][8192] or null
  __shared__ unsigned short xsm[2][16384];   // 2 x 32 KB x-tile
  __shared__ unsigned short wsm[2][16384];   // 2 x 32 KB W-tile (bf16)

  const int tid = threadIdx.x;
  const int lane = tid & 63, w = tid >> 6;
  const int mi = w >> 2, ni = w & 3;
  const int qr = lane & 15, quad = lane >> 4;
  const int n0 = blockIdx.x * TN;
  const int kz = blockIdx.y;
  const int kb = kz * KCHUNK;

  // W staging: thread reads 64 contiguous bytes of one W row per iter.
  const int trow = tid >> 2;                 // n-local 0..255
  const int tc = (tid & 3) * 16;             // col offset in BK
  const float* wrow = W + (size_t)(n0 + trow) * DK + kb + tc;
  const int ws_ = tc >> 5, q0 = (tc >> 3) & 3;
  const unsigned wA =
      (unsigned)(((ws_ * 16 + (trow >> 4)) * 64 + q0 * 16 + (trow & 15)) * 16);
  // x staging: 2 chunks/thread/iter, frag fx = w*2+j, wave-uniform + lane*16.
  const char* xg = (const char*)xb +
      ((size_t)(kz * 16) * 32 * 64 + (size_t)(w * 2) * 64 + lane) * 16;
  const unsigned xoff = (unsigned)(((w * 2) * 64 + lane) * 16);

  f32x4v acc[4][4];
#pragma unroll
  for (int a = 0; a < 4; ++a)
#pragma unroll
    for (int b = 0; b < 4; ++b) acc[a][b] = (f32x4v){0.f, 0.f, 0.f, 0.f};

  // prologue: W(0)->regs->wsm[0]; x(0)->xsm[0]
  float4 g0 = *(const float4*)(wrow);
  float4 g1 = *(const float4*)(wrow + 4);
  float4 g2 = *(const float4*)(wrow + 8);
  float4 g3 = *(const float4*)(wrow + 12);
  __builtin_amdgcn_global_load_lds((glbc_u8*)xg,
      (lds_u8*)((char*)xsm[0] + xoff), 16, 0, 0);
  __builtin_amdgcn_global_load_lds((glbc_u8*)(xg + 1024),
      (lds_u8*)((char*)xsm[0] + xoff + 1024), 16, 0, 0);
  *(bf16x8*)((char*)wsm[0] + wA) = pack8(g0, g1);
  *(bf16x8*)((char*)wsm[0] + wA + 256) = pack8(g2, g3);
  __syncthreads();

  for (int it = 0; it < NITER; ++it) {
    char* xcur = (char*)xsm[it & 1];
    char* xnxt = (char*)xsm[(it + 1) & 1];
    char* wcur = (char*)wsm[it & 1];
    char* wnxt = (char*)wsm[(it + 1) & 1];
    const bool havW = (it + 1 < NITER);
    if (havW) {
      const float* wsrc = wrow + (size_t)(it + 1) * BK;
      g0 = *(const float4*)(wsrc);
      g1 = *(const float4*)(wsrc + 4);
      g2 = *(const float4*)(wsrc + 8);
      g3 = *(const float4*)(wsrc + 12);
      const char* xs2 = xg + (size_t)(it + 1) * 32768;
      __builtin_amdgcn_global_load_lds((glbc_u8*)xs2,
          (lds_u8*)(xnxt + xoff), 16, 0, 0);
      __builtin_amdgcn_global_load_lds((glbc_u8*)(xs2 + 1024),
          (lds_u8*)(xnxt + xoff + 1024), 16, 0, 0);
    } else if (kz == 0) {
      // stage y frags for the LoRA iteration: 1 chunk/thread (16 KB)
      __builtin_amdgcn_global_load_lds(
          (glbc_u8*)((const char*)yb + (w * 64 + lane) * 16),
          (lds_u8*)(xnxt + (w * 64 + lane) * 16), 16, 0, 0);
    }
    // compute iter `it` from xcur/wcur (linear lane*16 ds_read_b128)
#pragma unroll
    for (int s = 0; s < 2; ++s) {
      bf16x8 a[4], b[4];
#pragma unroll
      for (int mt = 0; mt < 4; ++mt)
        a[mt] = *(const bf16x8*)(xcur + (((s * 16 + mi * 4 + mt) * 64 + lane) * 16));
#pragma unroll
      for (int sub = 0; sub < 4; ++sub)
        b[sub] = *(const bf16x8*)(wcur + (((s * 16 + ni * 4 + sub) * 64 + lane) * 16));
#pragma unroll
      for (int mt = 0; mt < 4; ++mt)
#pragma unroll
        for (int sub = 0; sub < 4; ++sub)
          acc[mt][sub] = __builtin_amdgcn_mfma_f32_16x16x32_bf16(
              a[mt], b[sub], acc[mt][sub], 0, 0, 0);
    }
    if (havW) {
      *(bf16x8*)(wnxt + wA) = pack8(g0, g1);
      *(bf16x8*)(wnxt + wA + 256) = pack8(g2, g3);
    }
    __syncthreads();
  }

  if (kz == 0) {  // LoRA: one K=32 MFMA round; y frags staged in xsm[0]
    const char* ybase = (const char*)xsm[0];
    bf16x8 b[4];
    float4 z = {0.f, 0.f, 0.f, 0.f};
#pragma unroll
    for (int sub = 0; sub < 4; ++sub) {
      int n_l = ni * 64 + sub * 16 + qr;
      const float* ap = Aw + (size_t)(n0 + n_l) * RLORA + quad * 8;
      float4 p0 = (quad < 2) ? *(const float4*)(ap) : z;
      float4 p1 = (quad < 2) ? *(const float4*)(ap + 4) : z;
      b[sub] = pack8(p0, p1);
    }
#pragma unroll
    for (int mt = 0; mt < 4; ++mt) {
      bf16x8 av = *(const bf16x8*)(ybase + (((mi * 4 + mt) * 64 + lane) * 16));
#pragma unroll
      for (int sub = 0; sub < 4; ++sub)
        acc[mt][sub] = __builtin_amdgcn_mfma_f32_16x16x32_bf16(
            av, b[sub], acc[mt][sub], 0, 0, 0);
    }
  }

  // epilogue: C/D col=lane&15 (n), row=quad*4+rg (m)  [m89-verified]
  if (part) {
    float* pb = part + (size_t)kz * DM * DN;
#pragma unroll
    for (int mt = 0; mt < 4; ++mt)
#pragma unroll
      for (int sub = 0; sub < 4; ++sub) {
        float* p = pb + (size_t)(mi * 64 + mt * 16 + quad * 4) * DN +
                   n0 + ni * 64 + sub * 16 + qr;
#pragma unroll
        for (int rg = 0; rg < 4; ++rg) p[(size_t)rg * DN] = acc[mt][sub][rg];
      }
  } else {
    float* ob = out;
#pragma unroll
    for (int mt = 0; mt < 4; ++mt)
#pragma unroll
      for (int sub = 0; sub < 4; ++sub) {
        float* p = ob + (size_t)(mi * 64 + mt * 16 + quad * 4) * DN +
                   n0 + ni * 64 + sub * 16 + qr;
#pragma unroll
        for (int rg = 0; rg < 4; ++rg) atomicAdd(p + (size_t)rg * DN, acc[mt][sub][rg]);
      }
  }
}

// out = sum_kz part[kz]  (fully overwrites out).  grid 2048 x 256.
__global__ __launch_bounds__(256) void reduce_k(
    const float* __restrict__ part, float* __restrict__ out) {
  size_t i = ((size_t)blockIdx.x * 256 + threadIdx.x) * 4;
  float4 s = *(const float4*)(part + i);
#pragma unroll
  for (int kzi = 1; kzi < KSPLIT; ++kzi) {
    float4 v = *(const float4*)(part + (size_t)kzi * DM * DN + i);
    s.x += v.x; s.y += v.y; s.z += v.z; s.w += v.w;
  }
  *(float4*)(out + i) = s;
}

// ---------------------------------------------------------------------------
extern "C" void kernel_launch(void* const* d_in, const int* in_sizes, int n_in,
                              void* d_out, int out_size, void* d_ws, size_t ws_size,
                              hipStream_t stream) {
  const float* x  = (const float*)d_in[0];   // [4,64,8192]
  const float* W  = (const float*)d_in[1];   // [8192,8192]
  const float* A  = (const float*)d_in[2];   // [8192,16]
  const float* Bm = (const float*)d_in[3];   // [16,8192]
  float* out = (float*)d_out;

  unsigned short* xb = (unsigned short*)d_ws;             // 4 MiB swizzled
  unsigned short* yb = (unsigned short*)((char*)d_ws + (4u << 20));  // 16 KiB
  float* y32 = (float*)((char*)yb + 16384);               // 16 KiB
  size_t base_bytes = (4u << 20) + 16384 + 16384;
  size_t part_bytes = (size_t)KSPLIT * DM * DN * 4;       // 64 MiB
  bool use_part = ws_size >= base_bytes + part_bytes;
  float* part = use_part ? (float*)((char*)d_ws + base_bytes) : nullptr;

  if (!use_part)
    hipMemsetAsync(d_out, 0, (size_t)out_size * sizeof(float), stream);
  hipMemsetAsync(y32, 0, (size_t)DM * RLORA * sizeof(float), stream);
  prep_x<<<dim3(8, 64), 256, 0, stream>>>(x, Bm, xb, y32);
  pack_y<<<4, 256, 0, stream>>>(y32, yb);
  lora_gemm<<<dim3(DN / TN, KSPLIT), 1024, 0, stream>>>(xb, W, yb, A, out, part);
  if (use_part) reduce_k<<<2048, 256, 0, stream>>>(part, out);
}

// Round 5
// 443.720 us; speedup vs baseline: 1.1868x; 1.0200x over previous
//
#include <hip/hip_runtime.h>
#include <stdint.h>

// out[m,n] = sum_k x[m,k]*W[n,k] + sum_r y[m,r]*A[n,r],  y = x @ B^T
// M=256, N=8192, K=8192, R=16. fp32 in/out; bf16 MFMA compute (thr 0.18).
//
// R5: tile 256m x 64n, 512 thr = 8 waves (4m x 2n), KSPLIT=4 -> 512 blocks
// = 2 blocks/CU (cross-block overlap of the barrier drain). W: global fp32
// prefetched 1 iter ahead in regs -> RNE pack -> LINEAR ds_write_b128
// (conflict-free) -> 8 KB bf16 double buffer. x: NO LDS -- per-wave a-frags
// as coalesced 16B global loads from frag-linear xb (L2-resident).

#define DM 256
#define DK 8192
#define DN 8192
#define RLORA 16

#define TN 64
#define BK 64
#define KSPLIT 4
#define KCHUNK (DK / KSPLIT)    // 2048
#define NITER (KCHUNK / BK)     // 32

typedef short bf16x8 __attribute__((ext_vector_type(8)));   // 4 VGPRs
typedef float f32x4v __attribute__((ext_vector_type(4)));

__device__ __forceinline__ unsigned short f2bf(float f) {
  unsigned u = __builtin_bit_cast(unsigned, f);
  u += 0x7FFFu + ((u >> 16) & 1u);           // RNE
  return (unsigned short)(u >> 16);
}

__device__ __forceinline__ bf16x8 pack8(float4 a, float4 b) {
  bf16x8 r;
  r[0] = (short)f2bf(a.x); r[1] = (short)f2bf(a.y);
  r[2] = (short)f2bf(a.z); r[3] = (short)f2bf(a.w);
  r[4] = (short)f2bf(b.x); r[5] = (short)f2bf(b.y);
  r[6] = (short)f2bf(b.z); r[7] = (short)f2bf(b.w);
  return r;
}

// ---------------------------------------------------------------------------
// prep_x: x -> bf16 in frag-linear chunk order, + partial y = x @ B^T.
// Chunk c = (K64*32 + s*16 + g)*64 + (oct*16 + r), 16 B, holding
// x[g*16+r][K64*64 + s*32 + oct*8 .. +8)  (A-operand layout: lane&15=m-row,
// lane>>4=k-octet).  grid (8, 64) x 256 thr.
__global__ __launch_bounds__(256) void prep_x(
    const float* __restrict__ x, const float* __restrict__ Bm,
    unsigned short* __restrict__ xb, float* __restrict__ y32) {
  const int ks = blockIdx.x;
  const int m0 = blockIdx.y * 4;
  const int t = threadIdx.x;
  const int k = ks * 1024 + t * 4;
  const int K64 = k >> 6, s = (k >> 5) & 1, oct = (k >> 3) & 3;
  const int e = k & 7;                       // 0 or 4
  float4 xv[4];
#pragma unroll
  for (int i = 0; i < 4; ++i) {
    const int m = m0 + i;
    const int g = m >> 4, r = m & 15;
    xv[i] = *(const float4*)(x + (size_t)m * DK + k);
    ushort4 h;
    h.x = f2bf(xv[i].x); h.y = f2bf(xv[i].y);
    h.z = f2bf(xv[i].z); h.w = f2bf(xv[i].w);
    const size_t chunk = (size_t)(K64 * 32 + s * 16 + g) * 64 + oct * 16 + r;
    *(ushort4*)(xb + chunk * 8 + e) = h;
  }
  float acc[4][RLORA];
#pragma unroll
  for (int r = 0; r < RLORA; ++r) {
    float4 b = *(const float4*)(Bm + (size_t)r * DK + k);
#pragma unroll
    for (int i = 0; i < 4; ++i)
      acc[i][r] = xv[i].x * b.x + xv[i].y * b.y + xv[i].z * b.z + xv[i].w * b.w;
  }
#pragma unroll
  for (int off = 32; off >= 1; off >>= 1)
#pragma unroll
    for (int i = 0; i < 4; ++i)
#pragma unroll
      for (int r = 0; r < RLORA; ++r)
        acc[i][r] += __shfl_xor(acc[i][r], off, 64);
  __shared__ float red[4][4][RLORA];
  const int lane = t & 63, wv = t >> 6;
  if (lane == 0) {
#pragma unroll
    for (int i = 0; i < 4; ++i)
#pragma unroll
      for (int r = 0; r < RLORA; ++r) red[wv][i][r] = acc[i][r];
  }
  __syncthreads();
  if (t < 64) {
    int i = t >> 4, r = t & 15;
    float sum = red[0][i][r] + red[1][i][r] + red[2][i][r] + red[3][i][r];
    atomicAdd(y32 + (m0 + i) * RLORA + r, sum);
  }
}

// y32 fp32 [256][16] -> yb A-operand frags (frag g = m/16, slot oct*16+r,
// cols oct*8+e, zero past 16).  16 KB.  grid 4 x 256.
__global__ __launch_bounds__(256) void pack_y(
    const float* __restrict__ y32, unsigned short* __restrict__ yb) {
  int slot = blockIdx.x * 256 + threadIdx.x;   // 16B slots
  int fy = slot >> 6, l = slot & 63;
  int oct = l >> 4, r = l & 15;
  int m = fy * 16 + r;
  unsigned short v[8];
#pragma unroll
  for (int e = 0; e < 8; ++e) {
    int c = oct * 8 + e;
    v[e] = (c < RLORA) ? f2bf(y32[m * RLORA + c]) : (unsigned short)0;
  }
  *(ushort4*)(yb + slot * 8) = make_ushort4(v[0], v[1], v[2], v[3]);
  *(ushort4*)(yb + slot * 8 + 4) = make_ushort4(v[4], v[5], v[6], v[7]);
}

// ---------------------------------------------------------------------------
// Main GEMM.  grid (128, 4), 512 thr = 8 waves as (mi = w>>1, ni = w&1).
__global__ __launch_bounds__(512, 4) void lora_gemm(
    const unsigned short* __restrict__ xb,   // frag-linear bf16 x
    const float* __restrict__ W,             // [8192][8192] fp32
    const unsigned short* __restrict__ yb,   // y frags (16 KB)
    const float* __restrict__ Aw,            // [8192][16] fp32
    float* __restrict__ out,                 // [256][8192] fp32
    float* __restrict__ part) {              // [KSPLIT][256][8192] or null
  __shared__ unsigned short wsm[2][4096];    // 2 x 8 KB bf16 W-tile

  const int tid = threadIdx.x;
  const int lane = tid & 63, w = tid >> 6;
  const int mi = w >> 1, ni = w & 1;
  const int qr = lane & 15, quad = lane >> 4;
  const int n0 = blockIdx.x * TN;
  const int kz = blockIdx.y;
  const int kb = kz * KCHUNK;

  // W staging: thread = frag F (tid>>6) x lane slot. F = s*4 + sub.
  // Reads W[n0 + sub*16 + qr][kb + it*64 + s*32 + quad*8 .. +8)  (32 B).
  const int Fs = w >> 2, Fsub = w & 3;
  const float* wsrc = W + (size_t)(n0 + Fsub * 16 + qr) * DK + kb +
                      Fs * 32 + quad * 8;
  // ds_write dest: (F*64 + lane)*16 = tid*16 -> perfectly linear.
  const unsigned wdst = (unsigned)tid * 16;

  // a-frag stream base: chunk (K64*32 + s*16 + g)*64 + lane, K64 = kz*32 + it
  const bf16x8* ap = (const bf16x8*)xb + ((size_t)(kz * 32) * 32) * 64 + lane;

  f32x4v acc[4][2];
#pragma unroll
  for (int a = 0; a < 4; ++a)
#pragma unroll
    for (int b = 0; b < 2; ++b) acc[a][b] = (f32x4v){0.f, 0.f, 0.f, 0.f};

  // prologue: W(0) -> regs -> wsm[0]
  float4 g0 = *(const float4*)(wsrc);
  float4 g1 = *(const float4*)(wsrc + 4);
  *(bf16x8*)((char*)wsm[0] + wdst) = pack8(g0, g1);
  __syncthreads();

  for (int it = 0; it < NITER; ++it) {
    const char* wcur = (const char*)wsm[it & 1];
    char* wnxt = (char*)wsm[(it + 1) & 1];
    const bool havW = (it + 1 < NITER);
    // (1) prefetch W(it+1) -- issued before compute, consumed after MFMAs
    if (havW) {
      const float* p = wsrc + (size_t)(it + 1) * BK;
      g0 = *(const float4*)(p);
      g1 = *(const float4*)(p + 4);
    }
    // (2) a-frags for this iter: 8 coalesced 16B loads from L2
    bf16x8 av[4][2];
#pragma unroll
    for (int s = 0; s < 2; ++s)
#pragma unroll
      for (int mt = 0; mt < 4; ++mt)
        av[mt][s] = ap[(size_t)(s * 16 + mi * 4 + mt) * 64];
    ap += (size_t)32 * 64;
    // (3) b-frags from LDS (linear lane*16, conflict-free) + (4) 16 MFMA
#pragma unroll
    for (int s = 0; s < 2; ++s) {
      bf16x8 b[2];
#pragma unroll
      for (int sub = 0; sub < 2; ++sub)
        b[sub] = *(const bf16x8*)(wcur +
            (((s * 4 + ni * 2 + sub) * 64 + lane) * 16));
#pragma unroll
      for (int mt = 0; mt < 4; ++mt)
#pragma unroll
        for (int sub = 0; sub < 2; ++sub)
          acc[mt][sub] = __builtin_amdgcn_mfma_f32_16x16x32_bf16(
              av[mt][s], b[sub], acc[mt][sub], 0, 0, 0);
    }
    // (5) pack W(it+1) -> other buffer (vmcnt wait hidden by MFMA phase)
    if (havW) *(bf16x8*)(wnxt + wdst) = pack8(g0, g1);
    __syncthreads();
  }

  if (kz == 0) {  // LoRA tail: one K=32 MFMA round (A cols >=16 zero)
    float4 z = {0.f, 0.f, 0.f, 0.f};
    bf16x8 b[2];
#pragma unroll
    for (int sub = 0; sub < 2; ++sub) {
      const float* ap2 = Aw + (size_t)(n0 + ni * 32 + sub * 16 + qr) * RLORA +
                         quad * 8;
      float4 p0 = (quad < 2) ? *(const float4*)(ap2) : z;
      float4 p1 = (quad < 2) ? *(const float4*)(ap2 + 4) : z;
      b[sub] = pack8(p0, p1);
    }
    const bf16x8* yp = (const bf16x8*)yb + lane;
#pragma unroll
    for (int mt = 0; mt < 4; ++mt) {
      bf16x8 av = yp[(size_t)(mi * 4 + mt) * 64];
#pragma unroll
      for (int sub = 0; sub < 2; ++sub)
        acc[mt][sub] = __builtin_amdgcn_mfma_f32_16x16x32_bf16(
            av, b[sub], acc[mt][sub], 0, 0, 0);
    }
  }

  // epilogue: C/D col=lane&15 (n), row=quad*4+rg (m)  [m89-verified]
  if (part) {
    float* pb = part + (size_t)kz * DM * DN;
#pragma unroll
    for (int mt = 0; mt < 4; ++mt)
#pragma unroll
      for (int sub = 0; sub < 2; ++sub) {
        float* p = pb + (size_t)(mi * 64 + mt * 16 + quad * 4) * DN +
                   n0 + ni * 32 + sub * 16 + qr;
#pragma unroll
        for (int rg = 0; rg < 4; ++rg) p[(size_t)rg * DN] = acc[mt][sub][rg];
      }
  } else {
    float* ob = out;
#pragma unroll
    for (int mt = 0; mt < 4; ++mt)
#pragma unroll
      for (int sub = 0; sub < 2; ++sub) {
        float* p = ob + (size_t)(mi * 64 + mt * 16 + quad * 4) * DN +
                   n0 + ni * 32 + sub * 16 + qr;
#pragma unroll
        for (int rg = 0; rg < 4; ++rg)
          atomicAdd(p + (size_t)rg * DN, acc[mt][sub][rg]);
      }
  }
}

// out = sum_kz part[kz]  (fully overwrites out).  grid 2048 x 256.
__global__ __launch_bounds__(256) void reduce_k(
    const float* __restrict__ part, float* __restrict__ out) {
  size_t i = ((size_t)blockIdx.x * 256 + threadIdx.x) * 4;
  float4 s = *(const float4*)(part + i);
#pragma unroll
  for (int kzi = 1; kzi < KSPLIT; ++kzi) {
    float4 v = *(const float4*)(part + (size_t)kzi * DM * DN + i);
    s.x += v.x; s.y += v.y; s.z += v.z; s.w += v.w;
  }
  *(float4*)(out + i) = s;
}

// ---------------------------------------------------------------------------
extern "C" void kernel_launch(void* const* d_in, const int* in_sizes, int n_in,
                              void* d_out, int out_size, void* d_ws, size_t ws_size,
                              hipStream_t stream) {
  const float* x  = (const float*)d_in[0];   // [4,64,8192]
  const float* W  = (const float*)d_in[1];   // [8192,8192]
  const float* A  = (const float*)d_in[2];   // [8192,16]
  const float* Bm = (const float*)d_in[3];   // [16,8192]
  float* out = (float*)d_out;

  unsigned short* xb = (unsigned short*)d_ws;             // 4 MiB swizzled
  unsigned short* yb = (unsigned short*)((char*)d_ws + (4u << 20));  // 16 KiB
  float* y32 = (float*)((char*)yb + 16384);               // 16 KiB
  size_t base_bytes = (4u << 20) + 16384 + 16384;
  size_t part_bytes = (size_t)KSPLIT * DM * DN * 4;       // 32 MiB
  bool use_part = ws_size >= base_bytes + part_bytes;
  float* part = use_part ? (float*)((char*)d_ws + base_bytes) : nullptr;

  if (!use_part)
    hipMemsetAsync(d_out, 0, (size_t)out_size * sizeof(float), stream);
  hipMemsetAsync(y32, 0, (size_t)DM * RLORA * sizeof(float), stream);
  prep_x<<<dim3(8, 64), 256, 0, stream>>>(x, Bm, xb, y32);
  pack_y<<<4, 256, 0, stream>>>(y32, yb);
  lora_gemm<<<dim3(DN / TN, KSPLIT), 512, 0, stream>>>(xb, W, yb, A, out, part);
  if (use_part) reduce_k<<<2048, 256, 0, stream>>>(part, out);
}